// Round 7
// baseline (257.235 us; speedup 1.0000x reference)
//
#include <hip/hip_runtime.h>

#define NPOS 384
#define DMODEL 512
#define NH 8
#define DK 64
#define BS 8
#define MROWS (BS * NPOS)     // 3072

typedef __attribute__((ext_vector_type(8))) short bf16x8;
typedef __attribute__((ext_vector_type(4))) float f32x4;

__device__ __forceinline__ unsigned short f2bf(float x) {
  unsigned int u = __float_as_uint(x);
  return (unsigned short)((u + 0x7fffu + ((u >> 16) & 1u)) >> 16);
}
__device__ __forceinline__ unsigned int pk2(float lo, float hi) {
  unsigned int ul = __float_as_uint(lo), uh = __float_as_uint(hi);
  ul = (ul + 0x7fffu + ((ul >> 16) & 1u)) >> 16;
  uh = (uh + 0x7fffu + ((uh >> 16) & 1u)) & 0xffff0000u;
  return ul | uh;
}
__device__ __forceinline__ bf16x8 pack8(float4 a, float4 b) {
  union { uint4 u; bf16x8 v; } cv;
  cv.u = make_uint4(pk2(a.x, a.y), pk2(a.z, a.w), pk2(b.x, b.y), pk2(b.z, b.w));
  return cv.v;
}

// ---------- K1: all input conversions in one launch ----------
// z 0..2: q/k/v f32 -> bf16 flat copy.  z 3..6: W[z-3] transpose -> bf16 [n][k].
__global__ __launch_bounds__(256) void convert_all(
    const float* __restrict__ qin, const float* __restrict__ kin,
    const float* __restrict__ vin,
    const float* __restrict__ Wq, const float* __restrict__ Wk,
    const float* __restrict__ Wv, const float* __restrict__ Wo,
    unsigned short* __restrict__ qkvb, unsigned short* __restrict__ wt) {
  const int z = blockIdx.y;
  const int t = threadIdx.x;
  if (z < 3) {
    const float* src = z == 0 ? qin : z == 1 ? kin : vin;
    unsigned short* dst = qkvb + (size_t)z * MROWS * DMODEL;
    const size_t i = ((size_t)blockIdx.x * 256 + t) * 8;
    float4 a = *(const float4*)&src[i];
    float4 b = *(const float4*)&src[i + 4];
    union { uint4 u; bf16x8 v; } cv;
    cv.u = make_uint4(pk2(a.x, a.y), pk2(a.z, a.w), pk2(b.x, b.y), pk2(b.z, b.w));
    *(uint4*)&dst[i] = cv.u;
    return;
  }
  if (blockIdx.x >= 64) return;
  __shared__ float s[64][68];
  const int w = z - 3;
  const float* W = w == 0 ? Wq : w == 1 ? Wk : w == 2 ? Wv : Wo;
  unsigned short* out = wt + (size_t)w * DMODEL * DMODEL;
  const int k0 = (blockIdx.x & 7) * 64, n0 = (blockIdx.x >> 3) * 64;
#pragma unroll
  for (int i = 0; i < 4; ++i) {
    int f = t + i * 256;
    int kr = f >> 4, q4 = f & 15;
    *(float4*)&s[kr][q4 * 4] = *(const float4*)&W[(size_t)(k0 + kr) * DMODEL + n0 + q4 * 4];
  }
  __syncthreads();
#pragma unroll
  for (int i = 0; i < 2; ++i) {
    int slot = t + i * 256;
    int n = slot >> 3, kq = slot & 7;
    unsigned int p[4];
#pragma unroll
    for (int j = 0; j < 4; ++j)
      p[j] = pk2(s[kq * 8 + j * 2][n], s[kq * 8 + j * 2 + 1][n]);
    *(uint4*)&out[(size_t)(n0 + n) * DMODEL + k0 + kq * 8] = make_uint4(p[0], p[1], p[2], p[3]);
  }
}

// ---------- K2: fused Q/K/V projections via MFMA (z selects), 64x64 tile ----------
__global__ __launch_bounds__(256) void proj_qkv(
    const unsigned short* __restrict__ qkvb,
    const unsigned short* __restrict__ wt,
    const float* __restrict__ bq, const float* __restrict__ bk, const float* __restrict__ bv,
    unsigned short* __restrict__ qhb, unsigned short* __restrict__ khb,
    float* __restrict__ origv, unsigned short* __restrict__ vhT) {
  __shared__ unsigned short As[64][72];
  __shared__ unsigned short Bs[64][72];
  const int z = blockIdx.z;
  const unsigned short* A = qkvb + (size_t)z * MROWS * DMODEL;
  const unsigned short* Wt = wt + (size_t)z * DMODEL * DMODEL;
  const float* bias = z == 0 ? bq : z == 1 ? bk : bv;
  const int m0 = blockIdx.x * 64, n0 = blockIdx.y * 64;
  const int t = threadIdx.x, lane = t & 63, w = t >> 6;
  const int wr = w >> 1, wc = w & 1;
  const int l15 = lane & 15, l4 = lane >> 4;
  f32x4 acc[2][2] = {};
  for (int kt = 0; kt < 8; ++kt) {
    const int k0 = kt * 64;
#pragma unroll
    for (int i = 0; i < 2; ++i) {
      int s = t + i * 256;
      int row = s >> 3, kq = s & 7;
      *(uint4*)&As[row][kq * 8] = *(const uint4*)&A[(size_t)(m0 + row) * DMODEL + k0 + kq * 8];
      *(uint4*)&Bs[row][kq * 8] = *(const uint4*)&Wt[(size_t)(n0 + row) * DMODEL + k0 + kq * 8];
    }
    __syncthreads();
    bf16x8 af[2][2], bfr[2][2];
#pragma unroll
    for (int mf = 0; mf < 2; ++mf)
#pragma unroll
      for (int ks = 0; ks < 2; ++ks)
        af[mf][ks] = *(const bf16x8*)&As[wr * 32 + mf * 16 + l15][ks * 32 + l4 * 8];
#pragma unroll
    for (int nf = 0; nf < 2; ++nf)
#pragma unroll
      for (int ks = 0; ks < 2; ++ks)
        bfr[nf][ks] = *(const bf16x8*)&Bs[wc * 32 + nf * 16 + l15][ks * 32 + l4 * 8];
#pragma unroll
    for (int mf = 0; mf < 2; ++mf)
#pragma unroll
      for (int nf = 0; nf < 2; ++nf)
#pragma unroll
        for (int ks = 0; ks < 2; ++ks)
          acc[mf][nf] = __builtin_amdgcn_mfma_f32_16x16x32_bf16(af[mf][ks], bfr[nf][ks],
                                                                acc[mf][nf], 0, 0, 0);
    __syncthreads();
  }
#pragma unroll
  for (int mf = 0; mf < 2; ++mf)
#pragma unroll
    for (int nf = 0; nf < 2; ++nf) {
      const int row0 = m0 + wr * 32 + mf * 16 + l4 * 4;
      const int col = n0 + wc * 32 + nf * 16 + l15;
      const float bi = bias[col];
      if (z == 0) {
#pragma unroll
        for (int i = 0; i < 4; ++i)
          qhb[(size_t)(row0 + i) * DMODEL + col] = f2bf((acc[mf][nf][i] + bi) * 0.125f);
      } else if (z == 1) {
#pragma unroll
        for (int i = 0; i < 4; ++i)
          khb[(size_t)(row0 + i) * DMODEL + col] = f2bf(acc[mf][nf][i] + bi);
      } else {
        const int b = row0 / NPOS, n = row0 - b * NPOS;
        const int h = col >> 6, d = col & 63;
        float vals[4];
#pragma unroll
        for (int i = 0; i < 4; ++i) {
          vals[i] = acc[mf][nf][i] + bi;
          origv[(size_t)(row0 + i) * DMODEL + col] = vals[i];
        }
        ushort4 pk;
        pk.x = f2bf(vals[0]); pk.y = f2bf(vals[1]);
        pk.z = f2bf(vals[2]); pk.w = f2bf(vals[3]);
        *(ushort4*)&vhT[((size_t)((b * NH + h) * DK + d)) * NPOS + n] = pk;
      }
    }
}

// ---------- K3: FUSED std scores + pos scores + softmax ----------
// grid (8 h, 384 n), block 256 = 4 waves; wave w owns m in [w*96, w*96+96).
// Per 16-m tile:
//   pos:  MFMA A = rk rows (HBM stream, f32->bf16 in-register),
//         B = q batch-cols (8 valid);  D[col=b][row=m_local].
//   std:  per-b MFMA A = khb rows m (L2-resident), B = q[b] broadcast in all
//         cols; result replicated across cols -> keep via (l15==b) select.
// Accumulate std+pos in registers, write f32 to LDS Pf. Then each wave
// softmaxes 2 of the 8 b-rows and writes bf16 P (second 1/8 folded in).
// rk is streamed from HBM exactly once across the grid.
__global__ __launch_bounds__(256) void pos_sm(
    const unsigned short* __restrict__ qhb,  // bf16 (b,n,h*64+d), prescaled 1/8
    const unsigned short* __restrict__ khb,  // bf16 (b,m,h*64+d)
    const float* __restrict__ rk,            // (n,m,h,d) f32
    unsigned short* __restrict__ P) {        // bf16 (b*8+h, n, m)
  __shared__ float Pf[8][392];
  const int h = blockIdx.x;
  const int n = blockIdx.y;
  const int t = threadIdx.x, lane = t & 63, w = t >> 6;
  const int l15 = lane & 15, l4 = lane >> 4;
  const int bcol = l15 & 7;
  // pos B fragments (q batch-cols), constant across m-tiles
  const unsigned short* qpb = qhb + ((size_t)bcol * NPOS + n) * DMODEL + h * DK;
  const bf16x8 pb0 = *(const bf16x8*)&qpb[l4 * 8];
  const bf16x8 pb1 = *(const bf16x8*)&qpb[32 + l4 * 8];
#pragma unroll 1
  for (int mt = 0; mt < 6; ++mt) {
    const int m0 = w * 96 + mt * 16;
    // pos: rk rows from HBM (issue loads first; MFMA on khb hides latency)
    const float* rkrow = rk + ((size_t)n * NPOS + m0 + l15) * (NH * DK) + h * DK;
    const float4 ra = *(const float4*)&rkrow[l4 * 8];
    const float4 rb = *(const float4*)&rkrow[l4 * 8 + 4];
    const float4 rc = *(const float4*)&rkrow[32 + l4 * 8];
    const float4 rd = *(const float4*)&rkrow[32 + l4 * 8 + 4];
    f32x4 keep = {};
    // std: per-b MFMA from L2-resident khb/qhb
#pragma unroll
    for (int b = 0; b < 8; ++b) {
      const unsigned short* kbase = khb + ((size_t)b * NPOS + m0 + l15) * DMODEL + h * DK;
      const unsigned short* qb = qhb + ((size_t)b * NPOS + n) * DMODEL + h * DK;
      f32x4 acc = {};
      acc = __builtin_amdgcn_mfma_f32_16x16x32_bf16(
          *(const bf16x8*)&kbase[l4 * 8], *(const bf16x8*)&qb[l4 * 8], acc, 0, 0, 0);
      acc = __builtin_amdgcn_mfma_f32_16x16x32_bf16(
          *(const bf16x8*)&kbase[32 + l4 * 8], *(const bf16x8*)&qb[32 + l4 * 8], acc, 0, 0, 0);
      if (l15 == b) {
        keep[0] += acc[0]; keep[1] += acc[1]; keep[2] += acc[2]; keep[3] += acc[3];
      }
    }
    // pos MFMAs
    keep = __builtin_amdgcn_mfma_f32_16x16x32_bf16(pack8(ra, rb), pb0, keep, 0, 0, 0);
    keep = __builtin_amdgcn_mfma_f32_16x16x32_bf16(pack8(rc, rd), pb1, keep, 0, 0, 0);
    if (l15 < 8)
      *(float4*)&Pf[l15][m0 + l4 * 4] = make_float4(keep[0], keep[1], keep[2], keep[3]);
  }
  __syncthreads();
  // softmax: wave w handles rows b = 2w, 2w+1
#pragma unroll
  for (int rr = 0; rr < 2; ++rr) {
    const int b = w * 2 + rr;
    float v[6];
    float mx = -1e30f;
#pragma unroll
    for (int j = 0; j < 6; ++j) {
      v[j] = Pf[b][j * 64 + lane];
      mx = fmaxf(mx, v[j]);
    }
#pragma unroll
    for (int o = 32; o; o >>= 1) mx = fmaxf(mx, __shfl_xor(mx, o, 64));
    float sum = 0.f;
#pragma unroll
    for (int j = 0; j < 6; ++j) {
      v[j] = __expf(v[j] - mx);
      sum += v[j];
    }
#pragma unroll
    for (int o = 32; o; o >>= 1) sum += __shfl_xor(sum, o, 64);
    const float inv = 0.125f / sum;
    unsigned short* prow = P + ((size_t)(b * NH + h) * NPOS + n) * NPOS;
#pragma unroll
    for (int j = 0; j < 6; ++j) prow[j * 64 + lane] = f2bf(v[j] * inv);
  }
}

// ---------- K4: PV NT MFMA: attn[b,n,h*64+d] = P[bh] @ vhT[bh]^T ----------
__global__ __launch_bounds__(256) void pv_nt(
    const unsigned short* __restrict__ P,      // bf16 [z][n][m], stride NPOS
    const unsigned short* __restrict__ vhT,    // bf16 [z][d][m]
    unsigned short* __restrict__ attb) {       // bf16 [3072][512]
  __shared__ unsigned short As[64][72];
  __shared__ unsigned short Bs[64][72];
  const int z = blockIdx.z, b = z >> 3, h = z & 7;
  const int n0 = blockIdx.x * 64;
  const unsigned short* Ag = P + ((size_t)z * NPOS + n0) * NPOS;
  const unsigned short* Bg = vhT + (size_t)z * DK * NPOS;
  const int t = threadIdx.x, lane = t & 63, w = t >> 6;
  const int wr = w >> 1, wc = w & 1;
  const int l15 = lane & 15, l4 = lane >> 4;
  f32x4 acc[2][2] = {};
  for (int kt = 0; kt < 6; ++kt) {
    const int k0 = kt * 64;
#pragma unroll
    for (int i = 0; i < 2; ++i) {
      int s = t + i * 256;
      int row = s >> 3, kq = s & 7;
      *(uint4*)&As[row][kq * 8] = *(const uint4*)&Ag[(size_t)row * NPOS + k0 + kq * 8];
      *(uint4*)&Bs[row][kq * 8] = *(const uint4*)&Bg[(size_t)row * NPOS + k0 + kq * 8];
    }
    __syncthreads();
    bf16x8 af[2][2], bfr[2][2];
#pragma unroll
    for (int mf = 0; mf < 2; ++mf)
#pragma unroll
      for (int ks = 0; ks < 2; ++ks)
        af[mf][ks] = *(const bf16x8*)&As[wr * 32 + mf * 16 + l15][ks * 32 + l4 * 8];
#pragma unroll
    for (int nf = 0; nf < 2; ++nf)
#pragma unroll
      for (int ks = 0; ks < 2; ++ks)
        bfr[nf][ks] = *(const bf16x8*)&Bs[wc * 32 + nf * 16 + l15][ks * 32 + l4 * 8];
#pragma unroll
    for (int mf = 0; mf < 2; ++mf)
#pragma unroll
      for (int nf = 0; nf < 2; ++nf)
#pragma unroll
        for (int ks = 0; ks < 2; ++ks)
          acc[mf][nf] = __builtin_amdgcn_mfma_f32_16x16x32_bf16(af[mf][ks], bfr[nf][ks],
                                                                acc[mf][nf], 0, 0, 0);
    __syncthreads();
  }
#pragma unroll
  for (int mf = 0; mf < 2; ++mf)
#pragma unroll
    for (int nf = 0; nf < 2; ++nf) {
      const int nn = n0 + wr * 32 + mf * 16 + l4 * 4;
      const int d = wc * 32 + nf * 16 + l15;
#pragma unroll
      for (int i = 0; i < 4; ++i)
        attb[(size_t)(b * NPOS + nn + i) * DMODEL + h * DK + d] = f2bf(acc[mf][nf][i]);
    }
}

// ---------- K5: output projection (A bf16), 64x64 tile ----------
__global__ __launch_bounds__(256) void proj_o(
    const unsigned short* __restrict__ attb, const unsigned short* __restrict__ WtO,
    const float* __restrict__ bo, float* __restrict__ outp) {
  __shared__ unsigned short As[64][72];
  __shared__ unsigned short Bs[64][72];
  const int m0 = blockIdx.x * 64, n0 = blockIdx.y * 64;
  const int t = threadIdx.x, lane = t & 63, w = t >> 6;
  const int wr = w >> 1, wc = w & 1;
  const int l15 = lane & 15, l4 = lane >> 4;
  f32x4 acc[2][2] = {};
  for (int kt = 0; kt < 8; ++kt) {
    const int k0 = kt * 64;
#pragma unroll
    for (int i = 0; i < 2; ++i) {
      int s = t + i * 256;
      int row = s >> 3, kq = s & 7;
      *(uint4*)&As[row][kq * 8] = *(const uint4*)&attb[(size_t)(m0 + row) * DMODEL + k0 + kq * 8];
      *(uint4*)&Bs[row][kq * 8] = *(const uint4*)&WtO[(size_t)(n0 + row) * DMODEL + k0 + kq * 8];
    }
    __syncthreads();
    bf16x8 af[2][2], bfr[2][2];
#pragma unroll
    for (int mf = 0; mf < 2; ++mf)
#pragma unroll
      for (int ks = 0; ks < 2; ++ks)
        af[mf][ks] = *(const bf16x8*)&As[wr * 32 + mf * 16 + l15][ks * 32 + l4 * 8];
#pragma unroll
    for (int nf = 0; nf < 2; ++nf)
#pragma unroll
      for (int ks = 0; ks < 2; ++ks)
        bfr[nf][ks] = *(const bf16x8*)&Bs[wc * 32 + nf * 16 + l15][ks * 32 + l4 * 8];
#pragma unroll
    for (int mf = 0; mf < 2; ++mf)
#pragma unroll
      for (int nf = 0; nf < 2; ++nf)
#pragma unroll
        for (int ks = 0; ks < 2; ++ks)
          acc[mf][nf] = __builtin_amdgcn_mfma_f32_16x16x32_bf16(af[mf][ks], bfr[nf][ks],
                                                                acc[mf][nf], 0, 0, 0);
    __syncthreads();
  }
#pragma unroll
  for (int mf = 0; mf < 2; ++mf)
#pragma unroll
    for (int nf = 0; nf < 2; ++nf) {
      const int row0 = m0 + wr * 32 + mf * 16 + l4 * 4;
      const int col = n0 + wc * 32 + nf * 16 + l15;
      const float bi = bo[col];
#pragma unroll
      for (int i = 0; i < 4; ++i)
        outp[(size_t)(row0 + i) * DMODEL + col] = acc[mf][nf][i] + bi;
    }
}

extern "C" void kernel_launch(void* const* d_in, const int* in_sizes, int n_in,
                              void* d_out, int out_size, void* d_ws, size_t ws_size,
                              hipStream_t stream) {
  const float* q  = (const float*)d_in[0];
  const float* k  = (const float*)d_in[1];
  const float* v  = (const float*)d_in[2];
  const float* rk = (const float*)d_in[3];
  // d_in[4] = rpos_v: unused by the reference
  const float* Wq = (const float*)d_in[5];
  const float* bq = (const float*)d_in[6];
  const float* Wk = (const float*)d_in[7];
  const float* bk = (const float*)d_in[8];
  const float* Wv = (const float*)d_in[9];
  const float* bv = (const float*)d_in[10];
  const float* Wo = (const float*)d_in[11];
  const float* bo = (const float*)d_in[12];

  const size_t TOK = (size_t)MROWS * DMODEL;  // 1,572,864
  unsigned short* wt   = (unsigned short*)d_ws;       // 4 * 512*512
  unsigned short* qhb  = wt + 4 * DMODEL * DMODEL;
  unsigned short* khb  = qhb + TOK;
  unsigned short* vhT  = khb + TOK;
  unsigned short* attb = vhT + TOK;
  unsigned short* P    = attb + TOK;                  // bf16 64*384*384 = 18.9 MB
  // bf16 copies of q,k,v inputs alias the P region (consumed by proj_qkv
  // before pos_sm writes P): 3*TOK ushorts = 9.4 MB < 18.9 MB.
  unsigned short* qkvb = P;
  float* origv = (float*)d_out;
  float* outp = origv + TOK;

  dim3 blk(256);

  convert_all<<<dim3(768, 7), blk, 0, stream>>>(q, k, v, Wq, Wk, Wv, Wo, qkvb, wt);
  proj_qkv<<<dim3(48, 8, 3), blk, 0, stream>>>(qkvb, wt, bq, bk, bv,
                                               qhb, khb, origv, vhT);
  pos_sm<<<dim3(8, 384), blk, 0, stream>>>(qhb, khb, rk, P);
  pv_nt<<<dim3(6, 1, 64), blk, 0, stream>>>(P, vhT, attb);
  proj_o<<<dim3(48, 8), blk, 0, stream>>>(attb, wt + 3 * DMODEL * DMODEL, bo, outp);
}

// Round 8
// 129.785 us; speedup vs baseline: 1.9820x; 1.9820x over previous
//
#include <hip/hip_runtime.h>

#define NPOS 384
#define DMODEL 512
#define NH 8
#define DK 64
#define BS 8
#define MROWS (BS * NPOS)     // 3072

typedef __attribute__((ext_vector_type(8))) short bf16x8;
typedef __attribute__((ext_vector_type(4))) float f32x4;

__device__ __forceinline__ unsigned short f2bf(float x) {
  unsigned int u = __float_as_uint(x);
  return (unsigned short)((u + 0x7fffu + ((u >> 16) & 1u)) >> 16);
}
__device__ __forceinline__ float bf2f(unsigned short x) {
  return __uint_as_float((unsigned int)x << 16);
}
__device__ __forceinline__ unsigned int pk2(float lo, float hi) {
  unsigned int ul = __float_as_uint(lo), uh = __float_as_uint(hi);
  ul = (ul + 0x7fffu + ((ul >> 16) & 1u)) >> 16;
  uh = (uh + 0x7fffu + ((uh >> 16) & 1u)) & 0xffff0000u;
  return ul | uh;
}
__device__ __forceinline__ bf16x8 pack8(float4 a, float4 b) {
  union { uint4 u; bf16x8 v; } cv;
  cv.u = make_uint4(pk2(a.x, a.y), pk2(a.z, a.w), pk2(b.x, b.y), pk2(b.z, b.w));
  return cv.v;
}

// ---------- K1: all input conversions in one launch ----------
// z 0..2: q/k/v f32 -> bf16 flat copy.  z 3..6: W[z-3] transpose -> bf16 [n][k].
__global__ __launch_bounds__(256) void convert_all(
    const float* __restrict__ qin, const float* __restrict__ kin,
    const float* __restrict__ vin,
    const float* __restrict__ Wq, const float* __restrict__ Wk,
    const float* __restrict__ Wv, const float* __restrict__ Wo,
    unsigned short* __restrict__ qkvb, unsigned short* __restrict__ wt) {
  const int z = blockIdx.y;
  const int t = threadIdx.x;
  if (z < 3) {
    const float* src = z == 0 ? qin : z == 1 ? kin : vin;
    unsigned short* dst = qkvb + (size_t)z * MROWS * DMODEL;
    const size_t i = ((size_t)blockIdx.x * 256 + t) * 8;
    float4 a = *(const float4*)&src[i];
    float4 b = *(const float4*)&src[i + 4];
    union { uint4 u; bf16x8 v; } cv;
    cv.u = make_uint4(pk2(a.x, a.y), pk2(a.z, a.w), pk2(b.x, b.y), pk2(b.z, b.w));
    *(uint4*)&dst[i] = cv.u;
    return;
  }
  if (blockIdx.x >= 64) return;
  __shared__ float s[64][68];
  const int w = z - 3;
  const float* W = w == 0 ? Wq : w == 1 ? Wk : w == 2 ? Wv : Wo;
  unsigned short* out = wt + (size_t)w * DMODEL * DMODEL;
  const int k0 = (blockIdx.x & 7) * 64, n0 = (blockIdx.x >> 3) * 64;
#pragma unroll
  for (int i = 0; i < 4; ++i) {
    int f = t + i * 256;
    int kr = f >> 4, q4 = f & 15;
    *(float4*)&s[kr][q4 * 4] = *(const float4*)&W[(size_t)(k0 + kr) * DMODEL + n0 + q4 * 4];
  }
  __syncthreads();
#pragma unroll
  for (int i = 0; i < 2; ++i) {
    int slot = t + i * 256;
    int n = slot >> 3, kq = slot & 7;
    unsigned int p[4];
#pragma unroll
    for (int j = 0; j < 4; ++j)
      p[j] = pk2(s[kq * 8 + j * 2][n], s[kq * 8 + j * 2 + 1][n]);
    *(uint4*)&out[(size_t)(n0 + n) * DMODEL + k0 + kq * 8] = make_uint4(p[0], p[1], p[2], p[3]);
  }
}

// ---------- K2: fused Q/K/V projections via MFMA (z selects), 64x64 tile ----------
__global__ __launch_bounds__(256) void proj_qkv(
    const unsigned short* __restrict__ qkvb,
    const unsigned short* __restrict__ wt,
    const float* __restrict__ bq, const float* __restrict__ bk, const float* __restrict__ bv,
    unsigned short* __restrict__ qhb, unsigned short* __restrict__ khb,
    float* __restrict__ origv, unsigned short* __restrict__ vhT) {
  __shared__ unsigned short As[64][72];
  __shared__ unsigned short Bs[64][72];
  const int z = blockIdx.z;
  const unsigned short* A = qkvb + (size_t)z * MROWS * DMODEL;
  const unsigned short* Wt = wt + (size_t)z * DMODEL * DMODEL;
  const float* bias = z == 0 ? bq : z == 1 ? bk : bv;
  const int m0 = blockIdx.x * 64, n0 = blockIdx.y * 64;
  const int t = threadIdx.x, lane = t & 63, w = t >> 6;
  const int wr = w >> 1, wc = w & 1;
  const int l15 = lane & 15, l4 = lane >> 4;
  f32x4 acc[2][2] = {};
  for (int kt = 0; kt < 8; ++kt) {
    const int k0 = kt * 64;
#pragma unroll
    for (int i = 0; i < 2; ++i) {
      int s = t + i * 256;
      int row = s >> 3, kq = s & 7;
      *(uint4*)&As[row][kq * 8] = *(const uint4*)&A[(size_t)(m0 + row) * DMODEL + k0 + kq * 8];
      *(uint4*)&Bs[row][kq * 8] = *(const uint4*)&Wt[(size_t)(n0 + row) * DMODEL + k0 + kq * 8];
    }
    __syncthreads();
    bf16x8 af[2][2], bfr[2][2];
#pragma unroll
    for (int mf = 0; mf < 2; ++mf)
#pragma unroll
      for (int ks = 0; ks < 2; ++ks)
        af[mf][ks] = *(const bf16x8*)&As[wr * 32 + mf * 16 + l15][ks * 32 + l4 * 8];
#pragma unroll
    for (int nf = 0; nf < 2; ++nf)
#pragma unroll
      for (int ks = 0; ks < 2; ++ks)
        bfr[nf][ks] = *(const bf16x8*)&Bs[wc * 32 + nf * 16 + l15][ks * 32 + l4 * 8];
#pragma unroll
    for (int mf = 0; mf < 2; ++mf)
#pragma unroll
      for (int nf = 0; nf < 2; ++nf)
#pragma unroll
        for (int ks = 0; ks < 2; ++ks)
          acc[mf][nf] = __builtin_amdgcn_mfma_f32_16x16x32_bf16(af[mf][ks], bfr[nf][ks],
                                                                acc[mf][nf], 0, 0, 0);
    __syncthreads();
  }
#pragma unroll
  for (int mf = 0; mf < 2; ++mf)
#pragma unroll
    for (int nf = 0; nf < 2; ++nf) {
      const int row0 = m0 + wr * 32 + mf * 16 + l4 * 4;
      const int col = n0 + wc * 32 + nf * 16 + l15;
      const float bi = bias[col];
      if (z == 0) {
#pragma unroll
        for (int i = 0; i < 4; ++i)
          qhb[(size_t)(row0 + i) * DMODEL + col] = f2bf((acc[mf][nf][i] + bi) * 0.125f);
      } else if (z == 1) {
#pragma unroll
        for (int i = 0; i < 4; ++i)
          khb[(size_t)(row0 + i) * DMODEL + col] = f2bf(acc[mf][nf][i] + bi);
      } else {
        const int b = row0 / NPOS, n = row0 - b * NPOS;
        const int h = col >> 6, d = col & 63;
        float vals[4];
#pragma unroll
        for (int i = 0; i < 4; ++i) {
          vals[i] = acc[mf][nf][i] + bi;
          origv[(size_t)(row0 + i) * DMODEL + col] = vals[i];
        }
        ushort4 pk;
        pk.x = f2bf(vals[0]); pk.y = f2bf(vals[1]);
        pk.z = f2bf(vals[2]); pk.w = f2bf(vals[3]);
        *(ushort4*)&vhT[((size_t)((b * NH + h) * DK + d)) * NPOS + n] = pk;
      }
    }
}

// ---------- K3: std scores NT MFMA -> bf16 S ----------
// tile 128x128, single K stage (K=64), 4 waves (2x2), wave 64x64.
__global__ __launch_bounds__(256) void scores_nt(
    const unsigned short* __restrict__ qhb, const unsigned short* __restrict__ khb,
    unsigned short* __restrict__ S) {
  __shared__ unsigned short As[128][72];
  __shared__ unsigned short Bs[128][72];
  const int z = blockIdx.z, b = z >> 3, h = z & 7;
  const unsigned short* Ag = qhb + (size_t)b * NPOS * DMODEL + h * DK;
  const unsigned short* Bg = khb + (size_t)b * NPOS * DMODEL + h * DK;
  const int n0 = blockIdx.x * 128, m0 = blockIdx.y * 128;
  const int t = threadIdx.x, lane = t & 63, w = t >> 6;
  const int wr = w >> 1, wc = w & 1;
  const int l15 = lane & 15, l4 = lane >> 4;
#pragma unroll
  for (int i = 0; i < 4; ++i) {
    int s = t + i * 256;
    int row = s >> 3, kq = s & 7;
    *(uint4*)&As[row][kq * 8] = *(const uint4*)&Ag[(size_t)(n0 + row) * DMODEL + kq * 8];
    *(uint4*)&Bs[row][kq * 8] = *(const uint4*)&Bg[(size_t)(m0 + row) * DMODEL + kq * 8];
  }
  __syncthreads();
  f32x4 acc[4][4] = {};
  bf16x8 af[4][2], bfr[4][2];
#pragma unroll
  for (int mf = 0; mf < 4; ++mf)
#pragma unroll
    for (int ks = 0; ks < 2; ++ks)
      af[mf][ks] = *(const bf16x8*)&As[wr * 64 + mf * 16 + l15][ks * 32 + l4 * 8];
#pragma unroll
  for (int nf = 0; nf < 4; ++nf)
#pragma unroll
    for (int ks = 0; ks < 2; ++ks)
      bfr[nf][ks] = *(const bf16x8*)&Bs[wc * 64 + nf * 16 + l15][ks * 32 + l4 * 8];
#pragma unroll
  for (int mf = 0; mf < 4; ++mf)
#pragma unroll
    for (int nf = 0; nf < 4; ++nf)
#pragma unroll
      for (int ks = 0; ks < 2; ++ks)
        acc[mf][nf] = __builtin_amdgcn_mfma_f32_16x16x32_bf16(af[mf][ks], bfr[nf][ks],
                                                              acc[mf][nf], 0, 0, 0);
  unsigned short* C = S + (size_t)z * NPOS * NPOS;
#pragma unroll
  for (int mf = 0; mf < 4; ++mf)
#pragma unroll
    for (int nf = 0; nf < 4; ++nf) {
      int rown = n0 + wr * 64 + mf * 16 + l4 * 4;
      int colm = m0 + wc * 64 + nf * 16 + l15;
#pragma unroll
      for (int i = 0; i < 4; ++i)
        C[(size_t)(rown + i) * NPOS + colm] = f2bf(acc[mf][nf][i]);
    }
}

// ---------- K4: FUSED pos scores + softmax (R6-proven form, bf16 S input) ----
// grid (8 h, 384 n), block 256 = 4 waves.
// Phase 1: pos[b][m] for all 384 m of this (h,n) via direct-register MFMA
//          (A = rk rows, B = q batch-cols; cols 8..15 discarded) -> LDS f32.
// Phase 2: each wave softmaxes 2 of the 8 b-rows: bf16 std row + LDS pos,
//          full-wave shfl reduce, write bf16 P (second 1/8 folded in).
// rk is streamed from HBM exactly once across the grid.
__global__ __launch_bounds__(256) void pos_sm(
    const unsigned short* __restrict__ qhb,  // bf16 (b,n,h*64+d), prescaled 1/8
    const unsigned short* __restrict__ S,    // bf16 (b*8+h, n, m) std scores
    const float* __restrict__ rk,            // (n,m,h,d) f32
    unsigned short* __restrict__ P) {        // bf16 (b*8+h, n, m)
  __shared__ float Pf[8][392];
  const int h = blockIdx.x;
  const int n = blockIdx.y;
  const int t = threadIdx.x, lane = t & 63, w = t >> 6;
  const int l15 = lane & 15, l4 = lane >> 4;
  const int bcol = l15 & 7;
  // B fragments (q batch-cols), constant across m-tiles
  const unsigned short* qpb = qhb + ((size_t)bcol * NPOS + n) * DMODEL + h * DK;
  const bf16x8 pb0 = *(const bf16x8*)&qpb[l4 * 8];
  const bf16x8 pb1 = *(const bf16x8*)&qpb[32 + l4 * 8];
  // phase 1: wave w covers m in [w*96, w*96+96)
#pragma unroll
  for (int mt = 0; mt < 6; ++mt) {
    const int m0 = w * 96 + mt * 16;
    const float* rkrow = rk + ((size_t)n * NPOS + m0 + l15) * (NH * DK) + h * DK;
    f32x4 acc = {};
    const float4 ra = *(const float4*)&rkrow[l4 * 8];
    const float4 rb = *(const float4*)&rkrow[l4 * 8 + 4];
    acc = __builtin_amdgcn_mfma_f32_16x16x32_bf16(pack8(ra, rb), pb0, acc, 0, 0, 0);
    const float4 rc = *(const float4*)&rkrow[32 + l4 * 8];
    const float4 rd = *(const float4*)&rkrow[32 + l4 * 8 + 4];
    acc = __builtin_amdgcn_mfma_f32_16x16x32_bf16(pack8(rc, rd), pb1, acc, 0, 0, 0);
    if (l15 < 8) {
#pragma unroll
      for (int i = 0; i < 4; ++i) Pf[l15][m0 + l4 * 4 + i] = acc[i];
    }
  }
  __syncthreads();
  // phase 2: wave w handles rows b = 2w, 2w+1
#pragma unroll
  for (int rr = 0; rr < 2; ++rr) {
    const int b = w * 2 + rr;
    const unsigned short* srow = S + ((size_t)(b * NH + h) * NPOS + n) * NPOS;
    unsigned short* prow = P + ((size_t)(b * NH + h) * NPOS + n) * NPOS;
    float v[6];
    float mx = -1e30f;
#pragma unroll
    for (int j = 0; j < 6; ++j) {
      v[j] = bf2f(srow[j * 64 + lane]) + Pf[b][j * 64 + lane];
      mx = fmaxf(mx, v[j]);
    }
#pragma unroll
    for (int o = 32; o; o >>= 1) mx = fmaxf(mx, __shfl_xor(mx, o, 64));
    float sum = 0.f;
#pragma unroll
    for (int j = 0; j < 6; ++j) {
      v[j] = __expf(v[j] - mx);
      sum += v[j];
    }
#pragma unroll
    for (int o = 32; o; o >>= 1) sum += __shfl_xor(sum, o, 64);
    const float inv = 0.125f / sum;
#pragma unroll
    for (int j = 0; j < 6; ++j) prow[j * 64 + lane] = f2bf(v[j] * inv);
  }
}

// ---------- K5: PV NT MFMA, 32-row n-tiles for occupancy ----------
// grid (12 n-tiles, 64 z). Block 256 = 4 waves (2x2), wave 16(n) x 32(d).
__global__ __launch_bounds__(256) void pv_nt(
    const unsigned short* __restrict__ P,      // bf16 [z][n][m], stride NPOS
    const unsigned short* __restrict__ vhT,    // bf16 [z][d][m]
    unsigned short* __restrict__ attb) {       // bf16 [3072][512]
  __shared__ unsigned short As[32][72];
  __shared__ unsigned short Bs[64][72];
  const int z = blockIdx.y, b = z >> 3, h = z & 7;
  const int n0 = blockIdx.x * 32;
  const unsigned short* Ag = P + ((size_t)z * NPOS + n0) * NPOS;
  const unsigned short* Bg = vhT + (size_t)z * DK * NPOS;
  const int t = threadIdx.x, lane = t & 63, w = t >> 6;
  const int wr = w >> 1, wc = w & 1;
  const int l15 = lane & 15, l4 = lane >> 4;
  f32x4 acc[2] = {};
  for (int kt = 0; kt < 6; ++kt) {
    const int k0 = kt * 64;
    {
      int rowA = t >> 3, kqA = t & 7;
      *(uint4*)&As[rowA][kqA * 8] = *(const uint4*)&Ag[(size_t)rowA * NPOS + k0 + kqA * 8];
#pragma unroll
      for (int i = 0; i < 2; ++i) {
        int s = t + i * 256;
        int row = s >> 3, kq = s & 7;
        *(uint4*)&Bs[row][kq * 8] = *(const uint4*)&Bg[(size_t)row * NPOS + k0 + kq * 8];
      }
    }
    __syncthreads();
    bf16x8 af[2], bfr[2][2];
#pragma unroll
    for (int ks = 0; ks < 2; ++ks)
      af[ks] = *(const bf16x8*)&As[wr * 16 + l15][ks * 32 + l4 * 8];
#pragma unroll
    for (int nf = 0; nf < 2; ++nf)
#pragma unroll
      for (int ks = 0; ks < 2; ++ks)
        bfr[nf][ks] = *(const bf16x8*)&Bs[wc * 32 + nf * 16 + l15][ks * 32 + l4 * 8];
#pragma unroll
    for (int nf = 0; nf < 2; ++nf)
#pragma unroll
      for (int ks = 0; ks < 2; ++ks)
        acc[nf] = __builtin_amdgcn_mfma_f32_16x16x32_bf16(af[ks], bfr[nf][ks],
                                                          acc[nf], 0, 0, 0);
    __syncthreads();
  }
#pragma unroll
  for (int nf = 0; nf < 2; ++nf) {
    const int nn = n0 + wr * 16 + l4 * 4;
    const int d = wc * 32 + nf * 16 + l15;
#pragma unroll
    for (int i = 0; i < 4; ++i)
      attb[(size_t)(b * NPOS + nn + i) * DMODEL + h * DK + d] = f2bf(acc[nf][i]);
  }
}

// ---------- K6: output projection (A bf16), 64x64 tile ----------
__global__ __launch_bounds__(256) void proj_o(
    const unsigned short* __restrict__ attb, const unsigned short* __restrict__ WtO,
    const float* __restrict__ bo, float* __restrict__ outp) {
  __shared__ unsigned short As[64][72];
  __shared__ unsigned short Bs[64][72];
  const int m0 = blockIdx.x * 64, n0 = blockIdx.y * 64;
  const int t = threadIdx.x, lane = t & 63, w = t >> 6;
  const int wr = w >> 1, wc = w & 1;
  const int l15 = lane & 15, l4 = lane >> 4;
  f32x4 acc[2][2] = {};
  for (int kt = 0; kt < 8; ++kt) {
    const int k0 = kt * 64;
#pragma unroll
    for (int i = 0; i < 2; ++i) {
      int s = t + i * 256;
      int row = s >> 3, kq = s & 7;
      *(uint4*)&As[row][kq * 8] = *(const uint4*)&attb[(size_t)(m0 + row) * DMODEL + k0 + kq * 8];
      *(uint4*)&Bs[row][kq * 8] = *(const uint4*)&WtO[(size_t)(n0 + row) * DMODEL + k0 + kq * 8];
    }
    __syncthreads();
    bf16x8 af[2][2], bfr[2][2];
#pragma unroll
    for (int mf = 0; mf < 2; ++mf)
#pragma unroll
      for (int ks = 0; ks < 2; ++ks)
        af[mf][ks] = *(const bf16x8*)&As[wr * 32 + mf * 16 + l15][ks * 32 + l4 * 8];
#pragma unroll
    for (int nf = 0; nf < 2; ++nf)
#pragma unroll
      for (int ks = 0; ks < 2; ++ks)
        bfr[nf][ks] = *(const bf16x8*)&Bs[wc * 32 + nf * 16 + l15][ks * 32 + l4 * 8];
#pragma unroll
    for (int mf = 0; mf < 2; ++mf)
#pragma unroll
      for (int nf = 0; nf < 2; ++nf)
#pragma unroll
        for (int ks = 0; ks < 2; ++ks)
          acc[mf][nf] = __builtin_amdgcn_mfma_f32_16x16x32_bf16(af[mf][ks], bfr[nf][ks],
                                                                acc[mf][nf], 0, 0, 0);
    __syncthreads();
  }
#pragma unroll
  for (int mf = 0; mf < 2; ++mf)
#pragma unroll
    for (int nf = 0; nf < 2; ++nf) {
      const int row0 = m0 + wr * 32 + mf * 16 + l4 * 4;
      const int col = n0 + wc * 32 + nf * 16 + l15;
      const float bi = bo[col];
#pragma unroll
      for (int i = 0; i < 4; ++i)
        outp[(size_t)(row0 + i) * DMODEL + col] = acc[mf][nf][i] + bi;
    }
}

extern "C" void kernel_launch(void* const* d_in, const int* in_sizes, int n_in,
                              void* d_out, int out_size, void* d_ws, size_t ws_size,
                              hipStream_t stream) {
  const float* q  = (const float*)d_in[0];
  const float* k  = (const float*)d_in[1];
  const float* v  = (const float*)d_in[2];
  const float* rk = (const float*)d_in[3];
  // d_in[4] = rpos_v: unused by the reference
  const float* Wq = (const float*)d_in[5];
  const float* bq = (const float*)d_in[6];
  const float* Wk = (const float*)d_in[7];
  const float* bk = (const float*)d_in[8];
  const float* Wv = (const float*)d_in[9];
  const float* bv = (const float*)d_in[10];
  const float* Wo = (const float*)d_in[11];
  const float* bo = (const float*)d_in[12];

  const size_t TOK = (size_t)MROWS * DMODEL;          // 1,572,864
  const size_t SEL = (size_t)BS * NH * NPOS * NPOS;   // 9,437,184
  unsigned short* wt   = (unsigned short*)d_ws;       // 4 * 512*512
  unsigned short* qhb  = wt + 4 * DMODEL * DMODEL;
  unsigned short* khb  = qhb + TOK;
  unsigned short* vhT  = khb + TOK;
  unsigned short* attb = vhT + TOK;
  unsigned short* S    = attb + TOK;                  // bf16 18.9 MB
  unsigned short* P    = S + SEL;                     // bf16 18.9 MB
  // bf16 copies of q,k,v inputs alias the P region (consumed by proj_qkv
  // before pos_sm writes P): 3*TOK ushorts = 9.4 MB < 18.9 MB.
  unsigned short* qkvb = P;
  float* origv = (float*)d_out;
  float* outp = origv + TOK;

  dim3 blk(256);

  convert_all<<<dim3(768, 7), blk, 0, stream>>>(q, k, v, Wq, Wk, Wv, Wo, qkvb, wt);
  proj_qkv<<<dim3(48, 8, 3), blk, 0, stream>>>(qkvb, wt, bq, bk, bv,
                                               qhb, khb, origv, vhT);
  scores_nt<<<dim3(3, 3, 64), blk, 0, stream>>>(qhb, khb, S);
  pos_sm<<<dim3(8, 384), blk, 0, stream>>>(qhb, S, rk, P);
  pv_nt<<<dim3(12, 64), blk, 0, stream>>>(P, vhT, attb);
  proj_o<<<dim3(48, 8), blk, 0, stream>>>(attb, wt + 3 * DMODEL * DMODEL, bo, outp);
}